// Round 1
// baseline (1798.676 us; speedup 1.0000x reference)
//
#include <hip/hip_runtime.h>
#include <hip/hip_bf16.h>
#include <math.h>

// Problem constants (B=2,S=2048 -> T=4096, H=1024, I=2048, E=8, top-2)
#define T_TOK 4096
#define H_DIM 1024
#define I_DIM 2048
#define E_NUM 8

#define BM 64
#define BN 64
#define BK 16

// ---------------- Router: logits, softmax, top-2, expert lists ----------------
__global__ __launch_bounds__(256) void router_kernel(
    const float* __restrict__ x, const float* __restrict__ gw,
    float* __restrict__ logits_out, int* __restrict__ counts,
    int* __restrict__ tok_list, float* __restrict__ w_list)
{
    int wave = threadIdx.x >> 6;
    int lane = threadIdx.x & 63;
    int t = blockIdx.x * 4 + wave;
    if (t >= T_TOK) return;

    float xs[16];
#pragma unroll
    for (int i = 0; i < 16; ++i) xs[i] = x[(size_t)t * H_DIM + i * 64 + lane];

    float lg[E_NUM];
#pragma unroll
    for (int e = 0; e < E_NUM; ++e) {
        float acc = 0.f;
#pragma unroll
        for (int i = 0; i < 16; ++i) acc += xs[i] * gw[e * H_DIM + i * 64 + lane];
#pragma unroll
        for (int off = 32; off >= 1; off >>= 1) acc += __shfl_xor(acc, off, 64);
        lg[e] = acc;
    }

    if (lane == 0) {
#pragma unroll
        for (int e = 0; e < E_NUM; ++e) logits_out[(size_t)t * E_NUM + e] = lg[e];
        // softmax (fp32, matches reference selection)
        float m = lg[0];
        for (int e = 1; e < E_NUM; ++e) m = fmaxf(m, lg[e]);
        float p[E_NUM]; float s = 0.f;
        for (int e = 0; e < E_NUM; ++e) { p[e] = expf(lg[e] - m); s += p[e]; }
        float invs = 1.f / s;
        for (int e = 0; e < E_NUM; ++e) p[e] *= invs;
        // top-2, strict > keeps lowest index on ties (lax.top_k semantics)
        int i0 = 0; float p0 = p[0];
        for (int e = 1; e < E_NUM; ++e) if (p[e] > p0) { p0 = p[e]; i0 = e; }
        int i1 = -1; float p1 = -1.f;
        for (int e = 0; e < E_NUM; ++e) { if (e == i0) continue; if (p[e] > p1) { p1 = p[e]; i1 = e; } }
        float inv = 1.f / (p0 + p1);
        float w0 = p0 * inv, w1 = p1 * inv;
        int pos0 = atomicAdd(&counts[i0], 1);
        tok_list[i0 * T_TOK + pos0] = t; w_list[i0 * T_TOK + pos0] = w0;
        int pos1 = atomicAdd(&counts[i1], 1);
        tok_list[i1 * T_TOK + pos1] = t; w_list[i1 * T_TOK + pos1] = w1;
    }
}

// ---------------- Offsets: 8-wide exclusive prefix ----------------
__global__ void offsets_kernel(const int* __restrict__ counts, int* __restrict__ offsets)
{
    if (threadIdx.x == 0 && blockIdx.x == 0) {
        int s = 0;
        for (int e = 0; e < E_NUM; ++e) { offsets[e] = s; s += counts[e]; }
    }
}

// ---------------- MLP1: h = silu(X Wg) * (X Wu), grouped per expert ----------------
__global__ __launch_bounds__(256) void mlp1_kernel(
    const float* __restrict__ x,
    const float* __restrict__ wg, const float* __restrict__ wu,
    const int* __restrict__ counts, const int* __restrict__ offsets,
    const int* __restrict__ tok_list,
    __hip_bfloat16* __restrict__ hbuf)
{
    int e = blockIdx.z;
    int cnt = counts[e];
    int m0 = blockIdx.y * BM;
    if (m0 >= cnt) return;
    int n0 = blockIdx.x * BN;
    int base = offsets[e];
    const float* Wg = wg + (size_t)e * H_DIM * I_DIM;
    const float* Wu = wu + (size_t)e * H_DIM * I_DIM;

    __shared__ float As[BK][BM];
    __shared__ float Bg[BK][BN];
    __shared__ float Bu[BK][BN];

    int tid = threadIdx.x;
    int tr = tid >> 4, tc = tid & 15;

    int la_k = tid & 15, la_r = tid >> 4;
    int tokr[4];
#pragma unroll
    for (int j = 0; j < 4; ++j) {
        int m = m0 + la_r + 16 * j;
        int mc = (m < cnt) ? m : (cnt - 1);
        tokr[j] = tok_list[e * T_TOK + mc];
    }
    int lb_n = tid & 63, lb_k = tid >> 6;

    float accg[4][4] = {}, accu[4][4] = {};

    for (int k0 = 0; k0 < H_DIM; k0 += BK) {
        __syncthreads();
#pragma unroll
        for (int j = 0; j < 4; ++j)
            As[la_k][la_r + 16 * j] = x[(size_t)tokr[j] * H_DIM + k0 + la_k];
#pragma unroll
        for (int j = 0; j < 4; ++j) {
            int kk = lb_k + 4 * j;
            Bg[kk][lb_n] = Wg[(size_t)(k0 + kk) * I_DIM + n0 + lb_n];
            Bu[kk][lb_n] = Wu[(size_t)(k0 + kk) * I_DIM + n0 + lb_n];
        }
        __syncthreads();
#pragma unroll
        for (int k = 0; k < BK; ++k) {
            float a[4], bg[4], bu[4];
#pragma unroll
            for (int i = 0; i < 4; ++i) a[i] = As[k][tr * 4 + i];
#pragma unroll
            for (int i = 0; i < 4; ++i) { bg[i] = Bg[k][tc * 4 + i]; bu[i] = Bu[k][tc * 4 + i]; }
#pragma unroll
            for (int i = 0; i < 4; ++i)
#pragma unroll
                for (int j = 0; j < 4; ++j) {
                    accg[i][j] += a[i] * bg[j];
                    accu[i][j] += a[i] * bu[j];
                }
        }
    }

#pragma unroll
    for (int i = 0; i < 4; ++i) {
        int m = m0 + tr * 4 + i;
        if (m < cnt) {
            size_t rowp = (size_t)(base + m) * I_DIM + n0 + tc * 4;
#pragma unroll
            for (int j = 0; j < 4; ++j) {
                float g = accg[i][j], u = accu[i][j];
                float hv = (g / (1.f + __expf(-g))) * u;
                hbuf[rowp + j] = __float2bfloat16(hv);
            }
        }
    }
}

// ---------------- MLP2: out += w * (h Wd), grouped per expert ----------------
__global__ __launch_bounds__(256) void mlp2_kernel(
    const __hip_bfloat16* __restrict__ hbuf,
    const float* __restrict__ wd,
    const int* __restrict__ counts, const int* __restrict__ offsets,
    const int* __restrict__ tok_list, const float* __restrict__ w_list,
    float* __restrict__ out)
{
    int e = blockIdx.z;
    int cnt = counts[e];
    int m0 = blockIdx.y * BM;
    if (m0 >= cnt) return;
    int n0 = blockIdx.x * BN;
    int base = offsets[e];
    const float* Wd = wd + (size_t)e * I_DIM * H_DIM;

    __shared__ float As[BK][BM];
    __shared__ float Bs[BK][BN];

    int tid = threadIdx.x;
    int tr = tid >> 4, tc = tid & 15;
    int la_k = tid & 15, la_r = tid >> 4;
    int rowc[4];
#pragma unroll
    for (int j = 0; j < 4; ++j) {
        int m = m0 + la_r + 16 * j;
        rowc[j] = base + ((m < cnt) ? m : (cnt - 1));
    }
    int lb_n = tid & 63, lb_k = tid >> 6;

    float acc[4][4] = {};
    for (int k0 = 0; k0 < I_DIM; k0 += BK) {
        __syncthreads();
#pragma unroll
        for (int j = 0; j < 4; ++j)
            As[la_k][la_r + 16 * j] = __bfloat162float(hbuf[(size_t)rowc[j] * I_DIM + k0 + la_k]);
#pragma unroll
        for (int j = 0; j < 4; ++j) {
            int kk = lb_k + 4 * j;
            Bs[kk][lb_n] = Wd[(size_t)(k0 + kk) * H_DIM + n0 + lb_n];
        }
        __syncthreads();
#pragma unroll
        for (int k = 0; k < BK; ++k) {
            float a[4], b[4];
#pragma unroll
            for (int i = 0; i < 4; ++i) a[i] = As[k][tr * 4 + i];
#pragma unroll
            for (int i = 0; i < 4; ++i) b[i] = Bs[k][tc * 4 + i];
#pragma unroll
            for (int i = 0; i < 4; ++i)
#pragma unroll
                for (int j = 0; j < 4; ++j) acc[i][j] += a[i] * b[j];
        }
    }

#pragma unroll
    for (int i = 0; i < 4; ++i) {
        int m = m0 + tr * 4 + i;
        if (m < cnt) {
            int t = tok_list[e * T_TOK + m];
            float w = w_list[e * T_TOK + m];
            float* op = out + (size_t)t * H_DIM + n0 + tc * 4;
#pragma unroll
            for (int j = 0; j < 4; ++j) atomicAdd(&op[j], w * acc[i][j]);
        }
    }
}

extern "C" void kernel_launch(void* const* d_in, const int* in_sizes, int n_in,
                              void* d_out, int out_size, void* d_ws, size_t ws_size,
                              hipStream_t stream)
{
    const float* x      = (const float*)d_in[0];   // [T,H]
    const float* gate_w = (const float*)d_in[1];   // [E,H]
    const float* w_gate = (const float*)d_in[2];   // [E,H,I]
    const float* w_up   = (const float*)d_in[3];   // [E,H,I]
    const float* w_down = (const float*)d_in[4];   // [E,I,H]

    float* out        = (float*)d_out;                       // [T,H]
    float* logits_out = out + (size_t)T_TOK * H_DIM;         // [T,E]

    // Workspace layout
    char* ws = (char*)d_ws;
    int*   counts   = (int*)ws;                              // 8 ints
    int*   offsets  = (int*)(ws + 64);                       // 8 ints
    int*   tok_list = (int*)(ws + 1024);                     // E*T ints
    float* w_list   = (float*)(ws + 1024 + E_NUM * T_TOK * 4);
    __hip_bfloat16* hbuf = (__hip_bfloat16*)(ws + (1 << 20)); // 2T x I bf16 = 32 MiB

    hipMemsetAsync(counts, 0, E_NUM * sizeof(int), stream);
    hipMemsetAsync(out, 0, (size_t)T_TOK * H_DIM * sizeof(float), stream);

    router_kernel<<<T_TOK / 4, 256, 0, stream>>>(x, gate_w, logits_out, counts, tok_list, w_list);
    offsets_kernel<<<1, 64, 0, stream>>>(counts, offsets);

    dim3 g1(I_DIM / BN, T_TOK / BM, E_NUM);
    mlp1_kernel<<<g1, 256, 0, stream>>>(x, w_gate, w_up, counts, offsets, tok_list, hbuf);

    dim3 g2(H_DIM / BN, T_TOK / BM, E_NUM);
    mlp2_kernel<<<g2, 256, 0, stream>>>(hbuf, w_down, counts, offsets, tok_list, w_list, out);
}

// Round 2
// 556.164 us; speedup vs baseline: 3.2341x; 3.2341x over previous
//
#include <hip/hip_runtime.h>
#include <hip/hip_bf16.h>
#include <math.h>

// Problem constants (B=2,S=2048 -> T=4096, H=1024, I=2048, E=8, top-2)
#define T_TOK 4096
#define H_DIM 1024
#define I_DIM 2048
#define E_NUM 8

typedef __bf16 bf16x8 __attribute__((ext_vector_type(8)));
typedef float  f32x4  __attribute__((ext_vector_type(4)));

// ---- helpers -------------------------------------------------------------
__device__ inline void gll16(const void* g, void* l) {
    __builtin_amdgcn_global_load_lds(
        (const __attribute__((address_space(1))) void*)g,
        (__attribute__((address_space(3))) void*)l, 16, 0, 0);
}

__device__ inline unsigned short f2bf(float f) {
    union { float f; unsigned u; } v; v.f = f;
    unsigned r = v.u + 0x7FFF + ((v.u >> 16) & 1);   // RNE
    return (unsigned short)(r >> 16);
}

// Stage a 128-row x 32-col bf16 tile (8 KB) into LDS via global_load_lds.
// Physical LDS layout: row-major, 64 B/row; k-group g_phys holds logical
// k-group g_phys ^ ((row>>1)&3)  (XOR swizzle -> 2-way banks on frag reads).
__device__ inline void stage_tile(const unsigned short* gbase, size_t stride_elems,
                                  int k0, char* smbase, int tid, int wv) {
#pragma unroll
    for (int it = 0; it < 2; ++it) {
        int idx = it * 256 + tid;            // 0..511, 16 B each
        int r   = idx >> 2;                  // tile row 0..127
        int kg  = (idx & 3) ^ ((r >> 1) & 3);// logical k-group for this slot
        const void* g = gbase + (size_t)r * stride_elems + k0 + kg * 8;
        void* l = smbase + it * 4096 + wv * 1024;   // wave-uniform base
        gll16(g, l);
    }
}

__device__ inline bf16x8 frag_ld(const char* smbase, int row, int q) {
    int kg = q ^ ((row >> 1) & 3);
    return *(const bf16x8*)(smbase + row * 64 + kg * 16);
}

// ---------------- Router ----------------
__global__ __launch_bounds__(256) void router_kernel(
    const float* __restrict__ x, const float* __restrict__ gw,
    float* __restrict__ logits_out, int* __restrict__ counts,
    int* __restrict__ tok_list, float* __restrict__ w_list)
{
    int wave = threadIdx.x >> 6;
    int lane = threadIdx.x & 63;
    int t = blockIdx.x * 4 + wave;
    if (t >= T_TOK) return;

    float xs[16];
#pragma unroll
    for (int i = 0; i < 16; ++i) xs[i] = x[(size_t)t * H_DIM + i * 64 + lane];

    float lg[E_NUM];
#pragma unroll
    for (int e = 0; e < E_NUM; ++e) {
        float acc = 0.f;
#pragma unroll
        for (int i = 0; i < 16; ++i) acc += xs[i] * gw[e * H_DIM + i * 64 + lane];
#pragma unroll
        for (int off = 32; off >= 1; off >>= 1) acc += __shfl_xor(acc, off, 64);
        lg[e] = acc;
    }

    if (lane == 0) {
#pragma unroll
        for (int e = 0; e < E_NUM; ++e) logits_out[(size_t)t * E_NUM + e] = lg[e];
        float m = lg[0];
        for (int e = 1; e < E_NUM; ++e) m = fmaxf(m, lg[e]);
        float p[E_NUM]; float s = 0.f;
        for (int e = 0; e < E_NUM; ++e) { p[e] = expf(lg[e] - m); s += p[e]; }
        float invs = 1.f / s;
        for (int e = 0; e < E_NUM; ++e) p[e] *= invs;
        int i0 = 0; float p0 = p[0];
        for (int e = 1; e < E_NUM; ++e) if (p[e] > p0) { p0 = p[e]; i0 = e; }
        int i1 = -1; float p1 = -1.f;
        for (int e = 0; e < E_NUM; ++e) { if (e == i0) continue; if (p[e] > p1) { p1 = p[e]; i1 = e; } }
        float inv = 1.f / (p0 + p1);
        int pos0 = atomicAdd(&counts[i0], 1);
        tok_list[i0 * T_TOK + pos0] = t; w_list[i0 * T_TOK + pos0] = p0 * inv;
        int pos1 = atomicAdd(&counts[i1], 1);
        tok_list[i1 * T_TOK + pos1] = t; w_list[i1 * T_TOK + pos1] = p1 * inv;
    }
}

// ---------------- Padded offsets (128-aligned per expert) ----------------
__global__ void offsets_kernel(const int* __restrict__ counts, int* __restrict__ poff)
{
    if (threadIdx.x == 0 && blockIdx.x == 0) {
        int s = 0;
        for (int e = 0; e < E_NUM; ++e) { poff[e] = s; s += ((counts[e] + 127) >> 7) << 7; }
    }
}

// ---------------- Gather x rows -> xg (bf16, padded slots) ----------------
__global__ __launch_bounds__(256) void gather_x(
    const float* __restrict__ x, const int* __restrict__ counts,
    const int* __restrict__ poff, const int* __restrict__ tok_list,
    unsigned short* __restrict__ xg)
{
    int e  = blockIdx.x >> 5;
    int mt = blockIdx.x & 31;
    int cnt = counts[e];
    int m0 = mt * 128;
    if (m0 >= cnt) return;
    int base = poff[e];
#pragma unroll 4
    for (int it = 0; it < 128; ++it) {
        int idx = it * 256 + threadIdx.x;    // 128 rows x 256 float4
        int r  = idx >> 8;
        int c4 = idx & 255;
        int m  = m0 + r;
        int mc = (m < cnt) ? m : cnt - 1;
        int t  = tok_list[e * T_TOK + mc];
        float4 v = *(const float4*)(x + (size_t)t * H_DIM + c4 * 4);
        unsigned short* o = xg + (size_t)(base + m) * H_DIM + c4 * 4;
        o[0] = f2bf(v.x); o[1] = f2bf(v.y); o[2] = f2bf(v.z); o[3] = f2bf(v.w);
    }
}

// ---------------- Transpose+convert: [K][N] fp32 -> [N][K] bf16 ----------------
__global__ __launch_bounds__(256) void transpose_cvt(
    const float* __restrict__ in, unsigned short* __restrict__ out, int K, int N)
{
    int e = blockIdx.z;
    in  += (size_t)e * K * N;
    out += (size_t)e * K * N;
    int k0 = blockIdx.y * 64, n0 = blockIdx.x * 64;
    __shared__ float t[64][65];
    int tc = threadIdx.x & 63, tr = threadIdx.x >> 6;
#pragma unroll
    for (int it = 0; it < 16; ++it) {
        int r = tr + it * 4;
        t[r][tc] = in[(size_t)(k0 + r) * N + n0 + tc];
    }
    __syncthreads();
#pragma unroll
    for (int it = 0; it < 16; ++it) {
        int n = tr + it * 4;
        out[(size_t)(n0 + n) * K + k0 + tc] = f2bf(t[tc][n]);
    }
}

// ---------------- MLP1: h = silu(X Wg) * (X Wu), MFMA grouped ----------------
__global__ __launch_bounds__(256, 2) void mlp1_kernel(
    const unsigned short* __restrict__ xg,
    const unsigned short* __restrict__ wgT, const unsigned short* __restrict__ wuT,
    const int* __restrict__ counts, const int* __restrict__ poff,
    unsigned short* __restrict__ hbuf)
{
    int e = blockIdx.z;
    int cnt = counts[e];
    int m0 = blockIdx.y * 128;
    if (m0 >= cnt) return;
    int n0 = blockIdx.x * 128;

    const unsigned short* A  = xg  + (size_t)(poff[e] + m0) * H_DIM;
    const unsigned short* Bg = wgT + (size_t)e * I_DIM * H_DIM + (size_t)n0 * H_DIM;
    const unsigned short* Bu = wuT + (size_t)e * I_DIM * H_DIM + (size_t)n0 * H_DIM;

    __shared__ char sm[24576];
    char* sA  = sm;
    char* sBg = sm + 8192;
    char* sBu = sm + 16384;

    int tid = threadIdx.x, lane = tid & 63, wv = tid >> 6;
    int wm = (wv >> 1) * 64, wn = (wv & 1) * 64;
    int q = lane >> 4, rl = lane & 15;

    f32x4 accg[4][4], accu[4][4];
#pragma unroll
    for (int i = 0; i < 4; ++i)
#pragma unroll
        for (int j = 0; j < 4; ++j) { accg[i][j] = (f32x4){0.f,0.f,0.f,0.f}; accu[i][j] = (f32x4){0.f,0.f,0.f,0.f}; }

    for (int k0 = 0; k0 < H_DIM; k0 += 32) {
        stage_tile(A,  H_DIM, k0, sA,  tid, wv);
        stage_tile(Bg, H_DIM, k0, sBg, tid, wv);
        stage_tile(Bu, H_DIM, k0, sBu, tid, wv);
        __syncthreads();

        bf16x8 af[4], bgf[4], buf_[4];
#pragma unroll
        for (int i = 0; i < 4; ++i) af[i]  = frag_ld(sA,  wm + i * 16 + rl, q);
#pragma unroll
        for (int j = 0; j < 4; ++j) { bgf[j] = frag_ld(sBg, wn + j * 16 + rl, q);
                                      buf_[j] = frag_ld(sBu, wn + j * 16 + rl, q); }
#pragma unroll
        for (int i = 0; i < 4; ++i)
#pragma unroll
            for (int j = 0; j < 4; ++j) {
                accg[i][j] = __builtin_amdgcn_mfma_f32_16x16x32_bf16(af[i], bgf[j], accg[i][j], 0, 0, 0);
                accu[i][j] = __builtin_amdgcn_mfma_f32_16x16x32_bf16(af[i], buf_[j], accu[i][j], 0, 0, 0);
            }
        __syncthreads();
    }

    size_t hrow0 = (size_t)(poff[e] + m0);
#pragma unroll
    for (int i = 0; i < 4; ++i)
#pragma unroll
        for (int p = 0; p < 4; ++p) {
            int row = wm + i * 16 + q * 4 + p;
            unsigned short* orow = hbuf + (hrow0 + row) * I_DIM + n0 + wn + rl;
#pragma unroll
            for (int j = 0; j < 4; ++j) {
                float g = accg[i][j][p], u = accu[i][j][p];
                float hv = g / (1.f + __expf(-g)) * u;
                orow[j * 16] = f2bf(hv);
            }
        }
}

// ---------------- MLP2: out += w * (h Wd), MFMA grouped ----------------
__global__ __launch_bounds__(256, 2) void mlp2_kernel(
    const unsigned short* __restrict__ hbuf,
    const unsigned short* __restrict__ wdT,
    const int* __restrict__ counts, const int* __restrict__ poff,
    const int* __restrict__ tok_list, const float* __restrict__ w_list,
    float* __restrict__ out)
{
    int e = blockIdx.z;
    int cnt = counts[e];
    int m0 = blockIdx.y * 128;
    if (m0 >= cnt) return;
    int n0 = blockIdx.x * 128;

    const unsigned short* A = hbuf + (size_t)(poff[e] + m0) * I_DIM;
    const unsigned short* B = wdT  + (size_t)e * H_DIM * I_DIM + (size_t)n0 * I_DIM;

    __shared__ char sm[16384];
    char* sA = sm;
    char* sB = sm + 8192;

    int tid = threadIdx.x, lane = tid & 63, wv = tid >> 6;
    int wm = (wv >> 1) * 64, wn = (wv & 1) * 64;
    int q = lane >> 4, rl = lane & 15;

    f32x4 acc[4][4];
#pragma unroll
    for (int i = 0; i < 4; ++i)
#pragma unroll
        for (int j = 0; j < 4; ++j) acc[i][j] = (f32x4){0.f,0.f,0.f,0.f};

    for (int k0 = 0; k0 < I_DIM; k0 += 32) {
        stage_tile(A, I_DIM, k0, sA, tid, wv);
        stage_tile(B, I_DIM, k0, sB, tid, wv);
        __syncthreads();

        bf16x8 af[4], bf[4];
#pragma unroll
        for (int i = 0; i < 4; ++i) af[i] = frag_ld(sA, wm + i * 16 + rl, q);
#pragma unroll
        for (int j = 0; j < 4; ++j) bf[j] = frag_ld(sB, wn + j * 16 + rl, q);
#pragma unroll
        for (int i = 0; i < 4; ++i)
#pragma unroll
            for (int j = 0; j < 4; ++j)
                acc[i][j] = __builtin_amdgcn_mfma_f32_16x16x32_bf16(af[i], bf[j], acc[i][j], 0, 0, 0);
        __syncthreads();
    }

#pragma unroll
    for (int i = 0; i < 4; ++i)
#pragma unroll
        for (int p = 0; p < 4; ++p) {
            int m = m0 + wm + i * 16 + q * 4 + p;
            if (m < cnt) {
                int   t = tok_list[e * T_TOK + m];
                float w = w_list[e * T_TOK + m];
                float* op = out + (size_t)t * H_DIM + n0 + wn + rl;
#pragma unroll
                for (int j = 0; j < 4; ++j) atomicAdd(op + j * 16, w * acc[i][j][p]);
            }
        }
}

extern "C" void kernel_launch(void* const* d_in, const int* in_sizes, int n_in,
                              void* d_out, int out_size, void* d_ws, size_t ws_size,
                              hipStream_t stream)
{
    const float* x      = (const float*)d_in[0];   // [T,H]
    const float* gate_w = (const float*)d_in[1];   // [E,H]
    const float* w_gate = (const float*)d_in[2];   // [E,H,I]
    const float* w_up   = (const float*)d_in[3];   // [E,H,I]
    const float* w_down = (const float*)d_in[4];   // [E,I,H]

    float* out        = (float*)d_out;                 // [T,H]
    float* logits_out = out + (size_t)T_TOK * H_DIM;   // [T,E]

    // Workspace layout
    char* ws = (char*)d_ws;
    int*   counts   = (int*)ws;                        // 8 ints
    int*   poff     = (int*)(ws + 64);                 // 8 ints (padded offsets)
    int*   tok_list = (int*)(ws + 1024);               // E*T ints
    float* w_list   = (float*)(ws + 1024 + E_NUM * T_TOK * 4);

    const size_t XG_ROWS = 9216;                       // 8192 + 8*128 padding
    const size_t OFF_XG = 1u << 20;
    const size_t OFF_HB = OFF_XG + XG_ROWS * H_DIM * 2;                 // xg: 18.9 MB
    const size_t OFF_WG = OFF_HB + XG_ROWS * I_DIM * 2;                 // hbuf: 37.7 MB
    const size_t OFF_WU = OFF_WG + (size_t)E_NUM * H_DIM * I_DIM * 2;   // 33.6 MB each
    const size_t OFF_WD = OFF_WU + (size_t)E_NUM * H_DIM * I_DIM * 2;

    unsigned short* xg   = (unsigned short*)(ws + OFF_XG);
    unsigned short* hbuf = (unsigned short*)(ws + OFF_HB);
    unsigned short* wgT  = (unsigned short*)(ws + OFF_WG);  // [E][I][H]
    unsigned short* wuT  = (unsigned short*)(ws + OFF_WU);  // [E][I][H]
    unsigned short* wdT  = (unsigned short*)(ws + OFF_WD);  // [E][H][I]

    hipMemsetAsync(counts, 0, E_NUM * sizeof(int), stream);
    hipMemsetAsync(out, 0, (size_t)T_TOK * H_DIM * sizeof(float), stream);

    router_kernel<<<T_TOK / 4, 256, 0, stream>>>(x, gate_w, logits_out, counts, tok_list, w_list);
    offsets_kernel<<<1, 64, 0, stream>>>(counts, poff);

    dim3 gt1(I_DIM / 64, H_DIM / 64, E_NUM);
    transpose_cvt<<<gt1, 256, 0, stream>>>(w_gate, wgT, H_DIM, I_DIM);
    transpose_cvt<<<gt1, 256, 0, stream>>>(w_up,   wuT, H_DIM, I_DIM);
    dim3 gt2(H_DIM / 64, I_DIM / 64, E_NUM);
    transpose_cvt<<<gt2, 256, 0, stream>>>(w_down, wdT, I_DIM, H_DIM);

    gather_x<<<E_NUM * 32, 256, 0, stream>>>(x, counts, poff, tok_list, xg);

    dim3 g1(I_DIM / 128, T_TOK / 128, E_NUM);
    mlp1_kernel<<<g1, 256, 0, stream>>>(xg, wgT, wuT, counts, poff, hbuf);

    dim3 g2(H_DIM / 128, T_TOK / 128, E_NUM);
    mlp2_kernel<<<g2, 256, 0, stream>>>(hbuf, wdT, counts, poff, tok_list, w_list, out);
}